// Round 10
// baseline (77.141 us; speedup 1.0000x reference)
//
#include <hip/hip_runtime.h>
#include <math.h>

#define H    2048
#define NE   64
#define TOKB 32
#define KC   32
#define NCH  64           // H / KC
#define NBUF 3
#define TAU  4.0e-3f
#define NEGF (-3.0e38f)

typedef __bf16 bf16x8 __attribute__((ext_vector_type(8)));
typedef float  f32x16 __attribute__((ext_vector_type(16)));

#define MFMA(a, b, c) __builtin_amdgcn_mfma_f32_32x32x16_bf16((a), (b), (c), 0, 0, 0)
#define LD4(p) (*reinterpret_cast<const float4*>(p))

// split fp32 octet (2x float4, consecutive k) into bf16 hi + lo
__device__ __forceinline__ void cvt8(const float4 a, const float4 b,
                                     bf16x8& hi, bf16x8& lo) {
    const float v0 = a.x, v1 = a.y, v2 = a.z, v3 = a.w;
    const float v4 = b.x, v5 = b.y, v6 = b.z, v7 = b.w;
    hi[0] = (__bf16)v0; lo[0] = (__bf16)(v0 - (float)hi[0]);
    hi[1] = (__bf16)v1; lo[1] = (__bf16)(v1 - (float)hi[1]);
    hi[2] = (__bf16)v2; lo[2] = (__bf16)(v2 - (float)hi[2]);
    hi[3] = (__bf16)v3; lo[3] = (__bf16)(v3 - (float)hi[3]);
    hi[4] = (__bf16)v4; lo[4] = (__bf16)(v4 - (float)hi[4]);
    hi[5] = (__bf16)v5; lo[5] = (__bf16)(v5 - (float)hi[5]);
    hi[6] = (__bf16)v6; lo[6] = (__bf16)(v6 - (float)hi[6]);
    hi[7] = (__bf16)v7; lo[7] = (__bf16)(v7 - (float)hi[7]);
}

// async 16B global -> LDS (per-lane global src, wave-uniform LDS base + lane*16)
__device__ __forceinline__ void gll16(const void* g, void* l) {
    __builtin_amdgcn_global_load_lds(
        (const __attribute__((address_space(1))) void*)g,
        (__attribute__((address_space(3))) void*)l, 16, 0, 0);
}

// ---- Pass 0: split W into bf16 hi|lo per 32-k chunk; zero worklist --------
// Wp layout (bf16): Wp[e*4096 + c*64 + (0..31 = hi | 32..63 = lo)]
__global__ __launch_bounds__(256) void prep_w(
    const float* __restrict__ w, __bf16* __restrict__ wp, int* __restrict__ wl)
{
    const int e   = blockIdx.x;
    const int tid = threadIdx.x;
    if (e == 0 && tid == 0) wl[0] = 0;
    const float4 a = LD4(&w[e * H + tid * 8]);
    const float4 b = LD4(&w[e * H + tid * 8 + 4]);
    bf16x8 hi, lo;
    cvt8(a, b, hi, lo);
    const int c  = tid >> 2;         // chunk (32 k)
    const int kk = (tid & 3) * 8;    // offset within chunk
    *reinterpret_cast<bf16x8*>(wp + e * 4096 + c * 64 + kk)      = hi;
    *reinterpret_cast<bf16x8*>(wp + e * 4096 + c * 64 + 32 + kk) = lo;
}

// ---- Pass 1: counted-vmcnt pipelined MFMA, prepacked-W ---------------------
// block: 256 thr / 4 waves = (e-tile 0/1) x (K-half 0/1); 32 tokens.
// Buffer (12 KB): A = 64 rows x 128B [hi 4 slots|lo 4 slots] bf16 @0,
//                 B = 32 rows x 128B (32 fp32) @8192. slot ^= row&7 both sides.
__global__ __launch_bounds__(256) void moe_gate_mfma(
    const float* __restrict__ x,      // [T, H] fp32
    const __bf16* __restrict__ wp,    // prepacked weights
    float* __restrict__ out, int woff,
    int* __restrict__ wl, int wlcap)
{
    __shared__ float4 lds4[NBUF][768];   // 3 x 12 KB

    const int tid  = threadIdx.x;
    const int lane = tid & 63;
    const int wv   = tid >> 6;
    const int et   = wv >> 1;         // e-tile: experts [et*32, +32)
    const int kq   = wv & 1;          // K-half of chunk (16 k each)
    const int lo5  = lane & 31;
    const int hi5  = lane >> 5;
    const int t0   = blockIdx.x * TOKB;

    // ---- staging sources (per-lane, pre-swizzled). +c*128 B walks chunks. --
    // s=0,1 -> A region (rows=experts); s=2 -> B region (rows=tokens)
    const char* sbase[3];
    #pragma unroll
    for (int s = 0; s < 3; ++s) {
        const int byte = (s * 256 + tid) * 16;
        if (byte < 8192) {
            const int row = byte >> 7;
            const int sl  = ((byte >> 4) & 7) ^ (row & 7);
            sbase[s] = (const char*)wp + (size_t)row * 8192 + sl * 16;
        } else {
            const int b   = byte - 8192;
            const int row = b >> 7;
            const int sl  = ((b >> 4) & 7) ^ (row & 7);
            sbase[s] = (const char*)x + (size_t)(t0 + row) * 8192 + sl * 16;
        }
    }

    f32x16 acc;
    #pragma unroll
    for (int i = 0; i < 16; ++i) acc[i] = 0.f;

    // prologue: stage chunks 0,1 (6 loads/wave outstanding)
    #pragma unroll
    for (int s = 0; s < 3; ++s) gll16(sbase[s],       &lds4[0][s * 256 + wv * 64]);
    #pragma unroll
    for (int s = 0; s < 3; ++s) gll16(sbase[s] + 128, &lds4[1][s * 256 + wv * 64]);

    // read-side byte offsets (swizzled)
    const int ra     = et * 32 + lo5;                 // expert row
    const int sA     = kq * 2 + hi5;                  // hi slot 0..3
    const int offAhi = ra * 128 + (((sA)     ^ (ra & 7)) << 4);
    const int offAlo = ra * 128 + (((4 + sA) ^ (ra & 7)) << 4);
    const int rb     = lo5;                           // token row
    const int sB     = kq * 4 + hi5 * 2;
    const int offB0  = 8192 + rb * 128 + (((sB)     ^ (rb & 7)) << 4);
    const int offB1  = 8192 + rb * 128 + (((sB + 1) ^ (rb & 7)) << 4);

    int ib = 0, iw = 2;
    for (int c = 0; c < NCH; ++c) {
        if (c < NCH - 1) {
            asm volatile("s_waitcnt vmcnt(3)" ::: "memory");  // own chunk-c landed
        } else {
            asm volatile("s_waitcnt vmcnt(0)" ::: "memory");
        }
        __builtin_amdgcn_s_barrier();     // all waves' chunk-c stages done

        const char* bufb = (const char*)&lds4[ib][0];
        const bf16x8 ahi = *reinterpret_cast<const bf16x8*>(bufb + offAhi);
        const bf16x8 alo = *reinterpret_cast<const bf16x8*>(bufb + offAlo);
        const float4 b1  = *reinterpret_cast<const float4*>(bufb + offB0);
        const float4 b2  = *reinterpret_cast<const float4*>(bufb + offB1);

        bf16x8 bh, bl;
        cvt8(b1, b2, bh, bl);

        if (c + 2 < NCH) {                // issue chunk c+2 (stays in flight)
            #pragma unroll
            for (int s = 0; s < 3; ++s)
                gll16(sbase[s] + (c + 2) * 128, &lds4[iw][s * 256 + wv * 64]);
        }

        acc = MFMA(ahi, bh, acc);         // hi*hi
        acc = MFMA(ahi, bl, acc);         // hi*lo
        acc = MFMA(alo, bh, acc);         // lo*hi

        ib = (ib == NBUF - 1) ? 0 : ib + 1;
        iw = (iw == NBUF - 1) ? 0 : iw + 1;
    }

    // ---- epilogue: scores -> S[32][65], then 32-thread scan ----------------
    __syncthreads();
    float* S = reinterpret_cast<float*>(&lds4[0][0]);   // 2080 floats < 12 KB
    if (kq == 0) {
        #pragma unroll
        for (int r = 0; r < 16; ++r) {
            const int e = et * 32 + (r & 3) + 8 * (r >> 2) + 4 * hi5;
            S[lo5 * 65 + e] = acc[r];
        }
    }
    __syncthreads();
    if (kq == 1) {
        #pragma unroll
        for (int r = 0; r < 16; ++r) {
            const int e = et * 32 + (r & 3) + 8 * (r >> 2) + 4 * hi5;
            S[lo5 * 65 + e] += acc[r];
        }
    }
    __syncthreads();

    if (tid < TOKB) {
        const float* row = &S[tid * 65];
        float m1 = NEGF, m2 = NEGF, m3 = NEGF;
        int   i1 = 0, i2 = 0;
        #pragma unroll
        for (int e = 0; e < NE; ++e) {    // ascending e, strict > = stable
            const float v = row[e];
            if (v > m1)      { m3 = m2; m2 = m1; i2 = i1; m1 = v; i1 = e; }
            else if (v > m2) { m3 = m2; m2 = v; i2 = e; }
            else if (v > m3) { m3 = v; }
        }
        const float r = expf(m2 - m1);
        const float s = 1.0f + r;
        const int   t = t0 + tid;
        out[2 * t + 0]        = (float)i1;
        out[2 * t + 1]        = (float)i2;
        out[woff + 2 * t + 0] = 1.0f / s;
        out[woff + 2 * t + 1] = r / s;
        if ((m1 - m2 < TAU) || (m2 - m3 < TAU)) {
            const int pos = atomicAdd(wl, 1);
            if (pos < wlcap) wl[1 + pos] = t;
        }
    }
}

// ---- Pass 2: fp64 refine, coalesced-W, block per token, 4-wave K-split ----
__global__ __launch_bounds__(256) void moe_refine_fp64(
    const float* __restrict__ x, const float* __restrict__ w,
    float* __restrict__ out, int woff,
    const int* __restrict__ wl, int wlcap)
{
    __shared__ double Sd[3][NE];
    const int lane = threadIdx.x & 63;
    const int wv   = threadIdx.x >> 6;
    const int ks   = wv * 512;
    int cnt = wl[0];
    if (cnt > wlcap) cnt = wlcap;

    for (int i = blockIdx.x; i < cnt; i += gridDim.x) {
        const int t = wl[1 + i];

        const float4 xa = LD4(&x[(size_t)t * H + ks + lane * 4]);
        const float4 xb = LD4(&x[(size_t)t * H + ks + 256 + lane * 4]);
        const double x0 = xa.x, x1 = xa.y, x2 = xa.z, x3 = xa.w;
        const double x4 = xb.x, x5 = xb.y, x6 = xb.z, x7 = xb.w;

        double myacc = 0.0;
        #pragma unroll 4
        for (int e = 0; e < NE; ++e) {
            const float4 wa = LD4(&w[(size_t)e * H + ks + lane * 4]);
            const float4 wb = LD4(&w[(size_t)e * H + ks + 256 + lane * 4]);
            double sA = 0.0, sB = 0.0;
            sA = fma((double)wa.x, x0, sA); sA = fma((double)wa.y, x1, sA);
            sA = fma((double)wa.z, x2, sA); sA = fma((double)wa.w, x3, sA);
            sB = fma((double)wb.x, x4, sB); sB = fma((double)wb.y, x5, sB);
            sB = fma((double)wb.z, x6, sB); sB = fma((double)wb.w, x7, sB);
            double s = sA + sB;
            #pragma unroll
            for (int off = 1; off < 64; off <<= 1)
                s += __shfl_xor(s, off);
            if (lane == e) myacc = s;
        }

        if (wv > 0) Sd[wv - 1][lane] = myacc;
        __syncthreads();
        if (wv == 0) {
            const double acc = ((myacc + Sd[0][lane]) + Sd[1][lane]) + Sd[2][lane];

            double v = acc; int bi = lane;
            #pragma unroll
            for (int off = 32; off > 0; off >>= 1) {
                double ov = __shfl_xor(v, off);
                int    oi = __shfl_xor(bi, off);
                if (ov > v || (ov == v && oi < bi)) { v = ov; bi = oi; }
            }
            const double m1 = v; const int i1 = bi;

            double v2 = (lane == i1) ? -1.0e300 : acc; int b2 = lane;
            #pragma unroll
            for (int off = 32; off > 0; off >>= 1) {
                double ov = __shfl_xor(v2, off);
                int    oi = __shfl_xor(b2, off);
                if (ov > v2 || (ov == v2 && oi < b2)) { v2 = ov; b2 = oi; }
            }
            const double m2 = v2; const int i2 = b2;

            if (lane == 0) {
                const double r = exp(m2 - m1);
                const double s = 1.0 + r;
                out[2 * t + 0]        = (float)i1;
                out[2 * t + 1]        = (float)i2;
                out[woff + 2 * t + 0] = (float)(1.0 / s);
                out[woff + 2 * t + 1] = (float)(r / s);
            }
        }
        __syncthreads();
    }
}

extern "C" void kernel_launch(void* const* d_in, const int* in_sizes, int n_in,
                              void* d_out, int out_size, void* d_ws, size_t ws_size,
                              hipStream_t stream) {
    const float* x   = (const float*)d_in[0];
    const float* wgt = (const float*)d_in[1];
    float* out = (float*)d_out;

    const int T    = in_sizes[0] / H;   // 16384
    const int woff = out_size / 2;      // 32768

    int*    wl = (int*)d_ws;                              // [1 + wlcap]
    __bf16* wp = (__bf16*)((char*)d_ws + 131072);         // 512 KB prepacked W
    int wlcap = T;
    if ((size_t)(131072) > ws_size) wlcap = 0;            // paranoia; ws is 512MB

    prep_w<<<dim3(NE), dim3(256), 0, stream>>>(wgt, wp, wl);

    moe_gate_mfma<<<dim3(T / TOKB), dim3(256), 0, stream>>>(
        x, wp, out, woff, wl, wlcap);

    moe_refine_fp64<<<dim3(512), dim3(256), 0, stream>>>(
        x, wgt, out, woff, wl, wlcap);
}

// Round 11
// 73.411 us; speedup vs baseline: 1.0508x; 1.0508x over previous
//
#include <hip/hip_runtime.h>
#include <math.h>

#define H    2048
#define NE   64
#define TOKB 64
#define KC   32
#define NCH  64           // H / KC
#define NBUF 4
#define TAU  4.0e-3f
#define NEGF (-3.0e38f)

typedef __bf16 bf16x8 __attribute__((ext_vector_type(8)));
typedef float  f32x16 __attribute__((ext_vector_type(16)));

#define MFMA(a, b, c) __builtin_amdgcn_mfma_f32_32x32x16_bf16((a), (b), (c), 0, 0, 0)
#define LD4(p) (*reinterpret_cast<const float4*>(p))

// split fp32 octet (2x float4, consecutive k) into bf16 hi + lo
__device__ __forceinline__ void cvt8(const float4 a, const float4 b,
                                     bf16x8& hi, bf16x8& lo) {
    const float v0 = a.x, v1 = a.y, v2 = a.z, v3 = a.w;
    const float v4 = b.x, v5 = b.y, v6 = b.z, v7 = b.w;
    hi[0] = (__bf16)v0; lo[0] = (__bf16)(v0 - (float)hi[0]);
    hi[1] = (__bf16)v1; lo[1] = (__bf16)(v1 - (float)hi[1]);
    hi[2] = (__bf16)v2; lo[2] = (__bf16)(v2 - (float)hi[2]);
    hi[3] = (__bf16)v3; lo[3] = (__bf16)(v3 - (float)hi[3]);
    hi[4] = (__bf16)v4; lo[4] = (__bf16)(v4 - (float)hi[4]);
    hi[5] = (__bf16)v5; lo[5] = (__bf16)(v5 - (float)hi[5]);
    hi[6] = (__bf16)v6; lo[6] = (__bf16)(v6 - (float)hi[6]);
    hi[7] = (__bf16)v7; lo[7] = (__bf16)(v7 - (float)hi[7]);
}

__device__ __forceinline__ void gll16(const void* g, void* l) {
    __builtin_amdgcn_global_load_lds(
        (const __attribute__((address_space(1))) void*)g,
        (__attribute__((address_space(3))) void*)l, 16, 0, 0);
}

// ---- Pass 0: prepack W -> bf16 hi|lo per 32-k chunk; zero worklist --------
// Wp layout (bf16): Wp[e*4096 + c*64 + (0..31 hi | 32..63 lo)]
__global__ __launch_bounds__(256) void prep_w(
    const float* __restrict__ w, __bf16* __restrict__ wp, int* __restrict__ wl)
{
    const int e   = blockIdx.x;
    const int tid = threadIdx.x;
    if (e == 0 && tid == 0) wl[0] = 0;
    const float4 a = LD4(&w[e * H + tid * 8]);
    const float4 b = LD4(&w[e * H + tid * 8 + 4]);
    bf16x8 hi, lo;
    cvt8(a, b, hi, lo);
    const int c  = tid >> 2;
    const int kk = (tid & 3) * 8;
    *reinterpret_cast<bf16x8*>(wp + e * 4096 + c * 64 + kk)      = hi;
    *reinterpret_cast<bf16x8*>(wp + e * 4096 + c * 64 + 32 + kk) = lo;
}

// ---- Pass 1: depth-3 counted-vmcnt pipelined MFMA, prepacked W -------------
// block: 256 thr / 4 waves = (m-half) x (K-half); 64 tokens x 64 experts.
// Buffer (16 KB): A = 64 expert rows x 128B bf16 [hi 4 slots|lo 4] @0,
//                 B = 64 token rows x 128B (32 fp32) @8192. slot ^= row&7.
__global__ __launch_bounds__(256) void moe_gate_mfma(
    const float* __restrict__ x,      // [T, H] fp32
    const __bf16* __restrict__ wp,    // prepacked weights
    float* __restrict__ out, int woff,
    int* __restrict__ wl, int wlcap)
{
    __shared__ float4 lds4[NBUF][1024];   // 4 x 16 KB = 64 KB

    const int tid  = threadIdx.x;
    const int lane = tid & 63;
    const int wv   = tid >> 6;
    const int mt   = wv >> 1;         // token half
    const int kh   = wv & 1;          // K half of chunk
    const int lo5  = lane & 31;
    const int hi5  = lane >> 5;
    const int t0   = blockIdx.x * TOKB;

    // ---- staging sources (per-lane, pre-swizzled); +c*128B walks chunks ----
    const char* sbase[4];
    #pragma unroll
    for (int s = 0; s < 4; ++s) {
        const int byte = (s * 256 + tid) * 16;           // 0..16383
        if (byte < 8192) {                               // A: expert rows
            const int row = byte >> 7;
            const int sl  = ((byte >> 4) & 7) ^ (row & 7);
            sbase[s] = (const char*)wp + (size_t)row * 8192 + sl * 16;
        } else {                                         // B: token rows
            const int b   = byte - 8192;
            const int row = b >> 7;
            const int sl  = ((b >> 4) & 7) ^ (row & 7);
            sbase[s] = (const char*)x + (size_t)(t0 + row) * 8192 + sl * 16;
        }
    }

    f32x16 acc0, acc1;
    #pragma unroll
    for (int i = 0; i < 16; ++i) { acc0[i] = 0.f; acc1[i] = 0.f; }

    // prologue: stage chunks 0,1,2 (12 loads/wave outstanding)
    #pragma unroll
    for (int p = 0; p < 3; ++p)
        #pragma unroll
        for (int s = 0; s < 4; ++s)
            gll16(sbase[s] + p * 128, &lds4[p][s * 256 + wv * 64]);

    // read-side byte offsets (swizzled)
    const int ra0 = lo5, ra1 = 32 + lo5;            // expert rows
    const int sA  = kh * 2 + hi5;                   // 16B slot 0..3
    const int offAh0 = ra0 * 128 + (((sA)     ^ (ra0 & 7)) << 4);
    const int offAl0 = ra0 * 128 + (((4 + sA) ^ (ra0 & 7)) << 4);
    const int offAh1 = ra1 * 128 + (((sA)     ^ (ra1 & 7)) << 4);
    const int offAl1 = ra1 * 128 + (((4 + sA) ^ (ra1 & 7)) << 4);
    const int rb  = mt * 32 + lo5;                  // token row
    const int sB  = kh * 4 + hi5 * 2;
    const int offB0 = 8192 + rb * 128 + (((sB)     ^ (rb & 7)) << 4);
    const int offB1 = 8192 + rb * 128 + (((sB + 1) ^ (rb & 7)) << 4);

    for (int c = 0; c < NCH; ++c) {
        if (c < NCH - 2) {
            asm volatile("s_waitcnt vmcnt(8)" ::: "memory");  // chunk c landed
        } else if (c == NCH - 2) {
            asm volatile("s_waitcnt vmcnt(4)" ::: "memory");
        } else {
            asm volatile("s_waitcnt vmcnt(0)" ::: "memory");
        }
        __builtin_amdgcn_s_barrier();

        const char* bufb = (const char*)&lds4[c & 3][0];
        const bf16x8 ah0 = *reinterpret_cast<const bf16x8*>(bufb + offAh0);
        const bf16x8 al0 = *reinterpret_cast<const bf16x8*>(bufb + offAl0);
        const bf16x8 ah1 = *reinterpret_cast<const bf16x8*>(bufb + offAh1);
        const bf16x8 al1 = *reinterpret_cast<const bf16x8*>(bufb + offAl1);
        const float4 b1  = *reinterpret_cast<const float4*>(bufb + offB0);
        const float4 b2  = *reinterpret_cast<const float4*>(bufb + offB1);

        bf16x8 bh, bl;
        cvt8(b1, b2, bh, bl);

        acc0 = MFMA(ah0, bh, acc0);    // hi*hi
        acc1 = MFMA(ah1, bh, acc1);
        acc0 = MFMA(ah0, bl, acc0);    // hi*lo
        acc1 = MFMA(ah1, bl, acc1);
        acc0 = MFMA(al0, bh, acc0);    // lo*hi
        acc1 = MFMA(al1, bh, acc1);

        if (c + 3 < NCH) {             // issue chunk c+3 (stays in flight)
            #pragma unroll
            for (int s = 0; s < 4; ++s)
                gll16(sbase[s] + (c + 3) * 128,
                      &lds4[(c + 3) & 3][s * 256 + wv * 64]);
        }
    }

    // ---- K-half reduction: kh==1 writes partials, kh==0 accumulates --------
    __syncthreads();
    float* S = reinterpret_cast<float*>(&lds4[0][0]);   // 64*65 floats < 64 KB
    if (kh == 1) {
        const int base = (mt * 32 + lo5) * 65;
        #pragma unroll
        for (int r = 0; r < 16; ++r) {
            const int e0 = (r & 3) + 8 * (r >> 2) + 4 * hi5;
            S[base + e0]      = acc0[r];
            S[base + 32 + e0] = acc1[r];
        }
    }
    __syncthreads();
    if (kh == 1) return;
    {
        const int base = (mt * 32 + lo5) * 65;
        #pragma unroll
        for (int r = 0; r < 16; ++r) {
            const int e0 = (r & 3) + 8 * (r >> 2) + 4 * hi5;
            acc0[r] += S[base + e0];
            acc1[r] += S[base + 32 + e0];
        }
    }

    // ---- per-lane top-3 over 32 held experts (e ascending => stable) -------
    float m1 = NEGF, m2 = NEGF, m3 = NEGF;
    int   i1 = 0, i2 = 0;
    #pragma unroll
    for (int r = 0; r < 16; ++r) {
        const float v = acc0[r];
        const int   e = (r & 3) + 8 * (r >> 2) + 4 * hi5;
        if (v > m1)      { m3 = m2; m2 = m1; i2 = i1; m1 = v; i1 = e; }
        else if (v > m2) { m3 = m2; m2 = v; i2 = e; }
        else if (v > m3) { m3 = v; }
    }
    #pragma unroll
    for (int r = 0; r < 16; ++r) {
        const float v = acc1[r];
        const int   e = 32 + (r & 3) + 8 * (r >> 2) + 4 * hi5;
        if (v > m1)      { m3 = m2; m2 = m1; i2 = i1; m1 = v; i1 = e; }
        else if (v > m2) { m3 = m2; m2 = v; i2 = e; }
        else if (v > m3) { m3 = v; }
    }

    // ---- merge sorted triples across lane pair (l, l^32): same token -------
    const float n1 = __shfl_xor(m1, 32), n2 = __shfl_xor(m2, 32), n3 = __shfl_xor(m3, 32);
    const int   j1 = __shfl_xor(i1, 32), j2 = __shfl_xor(i2, 32);

    float a1, a2, a3, b1, b2, b3; int ia1, ia2, ib1, ib2;
    const bool aF = (m1 > n1) || (m1 == n1 && i1 < j1);
    if (aF) { a1=m1; a2=m2; a3=m3; ia1=i1; ia2=i2; b1=n1; b2=n2; b3=n3; ib1=j1; ib2=j2; }
    else    { a1=n1; a2=n2; a3=n3; ia1=j1; ia2=j2; b1=m1; b2=m2; b3=m3; ib1=i1; ib2=i2; }

    const float o1 = a1; const int oi1 = ia1;
    float o2, o3; int oi2;
    const bool a2F = (a2 > b1) || (a2 == b1 && ia2 < ib1);
    if (a2F) { o2 = a2; oi2 = ia2; o3 = (a3 > b1) ? a3 : b1; }
    else     { o2 = b1; oi2 = ib1; o3 = (a2 > b2) ? a2 : b2; }

    if (hi5 == 0) {
        const int t = t0 + mt * 32 + lo5;
        const float r = expf(o2 - o1);
        const float s = 1.0f + r;
        out[2 * t + 0]        = (float)oi1;
        out[2 * t + 1]        = (float)oi2;
        out[woff + 2 * t + 0] = 1.0f / s;
        out[woff + 2 * t + 1] = r / s;
        if ((o1 - o2 < TAU) || (o2 - o3 < TAU)) {
            const int pos = atomicAdd(wl, 1);
            if (pos < wlcap) wl[1 + pos] = t;
        }
    }
}

// ---- Pass 2: fp64 refine, coalesced-W, block per token, 4-wave K-split ----
__global__ __launch_bounds__(256) void moe_refine_fp64(
    const float* __restrict__ x, const float* __restrict__ w,
    float* __restrict__ out, int woff,
    const int* __restrict__ wl, int wlcap)
{
    __shared__ double Sd[3][NE];
    const int lane = threadIdx.x & 63;
    const int wv   = threadIdx.x >> 6;
    const int ks   = wv * 512;
    int cnt = wl[0];
    if (cnt > wlcap) cnt = wlcap;

    for (int i = blockIdx.x; i < cnt; i += gridDim.x) {
        const int t = wl[1 + i];

        const float4 xa = LD4(&x[(size_t)t * H + ks + lane * 4]);
        const float4 xb = LD4(&x[(size_t)t * H + ks + 256 + lane * 4]);
        const double x0 = xa.x, x1 = xa.y, x2 = xa.z, x3 = xa.w;
        const double x4 = xb.x, x5 = xb.y, x6 = xb.z, x7 = xb.w;

        double myacc = 0.0;
        #pragma unroll 4
        for (int e = 0; e < NE; ++e) {
            const float4 wa = LD4(&w[(size_t)e * H + ks + lane * 4]);
            const float4 wb = LD4(&w[(size_t)e * H + ks + 256 + lane * 4]);
            double sA = 0.0, sB = 0.0;
            sA = fma((double)wa.x, x0, sA); sA = fma((double)wa.y, x1, sA);
            sA = fma((double)wa.z, x2, sA); sA = fma((double)wa.w, x3, sA);
            sB = fma((double)wb.x, x4, sB); sB = fma((double)wb.y, x5, sB);
            sB = fma((double)wb.z, x6, sB); sB = fma((double)wb.w, x7, sB);
            double s = sA + sB;
            #pragma unroll
            for (int off = 1; off < 64; off <<= 1)
                s += __shfl_xor(s, off);
            if (lane == e) myacc = s;
        }

        if (wv > 0) Sd[wv - 1][lane] = myacc;
        __syncthreads();
        if (wv == 0) {
            const double acc = ((myacc + Sd[0][lane]) + Sd[1][lane]) + Sd[2][lane];

            double v = acc; int bi = lane;
            #pragma unroll
            for (int off = 32; off > 0; off >>= 1) {
                double ov = __shfl_xor(v, off);
                int    oi = __shfl_xor(bi, off);
                if (ov > v || (ov == v && oi < bi)) { v = ov; bi = oi; }
            }
            const double m1 = v; const int i1 = bi;

            double v2 = (lane == i1) ? -1.0e300 : acc; int b2 = lane;
            #pragma unroll
            for (int off = 32; off > 0; off >>= 1) {
                double ov = __shfl_xor(v2, off);
                int    oi = __shfl_xor(b2, off);
                if (ov > v2 || (ov == v2 && oi < b2)) { v2 = ov; b2 = oi; }
            }
            const double m2 = v2; const int i2 = b2;

            if (lane == 0) {
                const double r = exp(m2 - m1);
                const double s = 1.0 + r;
                out[2 * t + 0]        = (float)i1;
                out[2 * t + 1]        = (float)i2;
                out[woff + 2 * t + 0] = (float)(1.0 / s);
                out[woff + 2 * t + 1] = (float)(r / s);
            }
        }
        __syncthreads();
    }
}

extern "C" void kernel_launch(void* const* d_in, const int* in_sizes, int n_in,
                              void* d_out, int out_size, void* d_ws, size_t ws_size,
                              hipStream_t stream) {
    const float* x   = (const float*)d_in[0];
    const float* wgt = (const float*)d_in[1];
    float* out = (float*)d_out;

    const int T    = in_sizes[0] / H;   // 16384
    const int woff = out_size / 2;      // 32768

    int*    wl = (int*)d_ws;
    __bf16* wp = (__bf16*)((char*)d_ws + 131072);   // 512 KB prepacked W
    int wlcap = T;

    prep_w<<<dim3(NE), dim3(256), 0, stream>>>(wgt, wp, wl);

    moe_gate_mfma<<<dim3(T / TOKB), dim3(256), 0, stream>>>(
        x, wp, out, woff, wl, wlcap);

    moe_refine_fp64<<<dim3(512), dim3(256), 0, stream>>>(
        x, wgt, out, woff, wl, wlcap);
}

// Round 12
// 60.749 us; speedup vs baseline: 1.2698x; 1.2084x over previous
//
#include <hip/hip_runtime.h>
#include <math.h>

#define H    2048
#define NE   64
#define TOKB 64
#define KC   64
#define NCH  32           // H / KC
#define NBUF 4
#define TAU  4.0e-3f
#define NEGF (-3.0e38f)

typedef __bf16 bf16x8 __attribute__((ext_vector_type(8)));
typedef float  f32x16 __attribute__((ext_vector_type(16)));

#define MFMA(a, b, c) __builtin_amdgcn_mfma_f32_32x32x16_bf16((a), (b), (c), 0, 0, 0)
#define LD4(p) (*reinterpret_cast<const float4*>(p))

// split fp32 octet (2x float4, consecutive k) into bf16 hi + lo
__device__ __forceinline__ void cvt8(const float4 a, const float4 b,
                                     bf16x8& hi, bf16x8& lo) {
    const float v0 = a.x, v1 = a.y, v2 = a.z, v3 = a.w;
    const float v4 = b.x, v5 = b.y, v6 = b.z, v7 = b.w;
    hi[0] = (__bf16)v0; lo[0] = (__bf16)(v0 - (float)hi[0]);
    hi[1] = (__bf16)v1; lo[1] = (__bf16)(v1 - (float)hi[1]);
    hi[2] = (__bf16)v2; lo[2] = (__bf16)(v2 - (float)hi[2]);
    hi[3] = (__bf16)v3; lo[3] = (__bf16)(v3 - (float)hi[3]);
    hi[4] = (__bf16)v4; lo[4] = (__bf16)(v4 - (float)hi[4]);
    hi[5] = (__bf16)v5; lo[5] = (__bf16)(v5 - (float)hi[5]);
    hi[6] = (__bf16)v6; lo[6] = (__bf16)(v6 - (float)hi[6]);
    hi[7] = (__bf16)v7; lo[7] = (__bf16)(v7 - (float)hi[7]);
}

__device__ __forceinline__ void gll16(const void* g, void* l) {
    __builtin_amdgcn_global_load_lds(
        (const __attribute__((address_space(1))) void*)g,
        (__attribute__((address_space(3))) void*)l, 16, 0, 0);
}

// ---- Pass 0: prepack W -> bf16 hi|lo per 32-k subchunk; zero worklist -----
// Wp (bf16): Wp[e*4096 + c32*64 + (0..31 hi | 32..63 lo)]; row = 8192 B
__global__ __launch_bounds__(256) void prep_w(
    const float* __restrict__ w, __bf16* __restrict__ wp, int* __restrict__ wl)
{
    const int e   = blockIdx.x;
    const int tid = threadIdx.x;
    if (e == 0 && tid == 0) wl[0] = 0;
    const float4 a = LD4(&w[e * H + tid * 8]);
    const float4 b = LD4(&w[e * H + tid * 8 + 4]);
    bf16x8 hi, lo;
    cvt8(a, b, hi, lo);
    const int c  = tid >> 2;
    const int kk = (tid & 3) * 8;
    *reinterpret_cast<bf16x8*>(wp + e * 4096 + c * 64 + kk)      = hi;
    *reinterpret_cast<bf16x8*>(wp + e * 4096 + c * 64 + 32 + kk) = lo;
}

// ---- Pass 1: 8-wave deep-pipeline MFMA, 128 KB dynamic LDS -----------------
// block: 512 thr / 8 waves = (m-half) x (K-slice 0..3); 64 tokens x 64 experts.
// Buffer (32 KB): A = 64 expert rows x 256B bf16 [hi32|lo32|hi32|lo32] @0,
//                 B = 64 token rows x 256B (64 fp32) @16384.
// 16B-slot swizzle: slot ^= row & 15 (both staging source and read side).
__global__ __launch_bounds__(512) void moe_gate_mfma(
    const float* __restrict__ x,      // [T, H] fp32
    const __bf16* __restrict__ wp,    // prepacked weights
    float* __restrict__ out, int woff,
    int* __restrict__ wl, int wlcap)
{
    extern __shared__ char lds[];     // NBUF x 32768 = 131072 B

    const int tid  = threadIdx.x;
    const int lane = tid & 63;
    const int wv   = tid >> 6;        // 0..7
    const int mt   = wv >> 2;         // token half
    const int kq   = wv & 3;          // K-slice (16 k) within 64-k chunk
    const int lo5  = lane & 31;
    const int hi5  = lane >> 5;
    const int t0   = blockIdx.x * TOKB;

    // ---- staging sources (per-lane, pre-swizzled); +c*256B walks chunks ----
    const char* sbase[4];
    #pragma unroll
    for (int s = 0; s < 4; ++s) {
        const int byte = ((wv * 4 + s) * 64 + lane) * 16;   // 0..32767
        if (byte < 16384) {                                 // A: expert rows
            const int row = byte >> 8;
            const int sl  = ((byte >> 4) & 15) ^ (row & 15);
            sbase[s] = (const char*)wp + (size_t)row * 8192 + sl * 16;
        } else {                                            // B: token rows
            const int b   = byte - 16384;
            const int row = b >> 8;
            const int sl  = ((b >> 4) & 15) ^ (row & 15);
            sbase[s] = (const char*)x + (size_t)(t0 + row) * 8192 + sl * 16;
        }
    }

    f32x16 acc0, acc1;
    #pragma unroll
    for (int i = 0; i < 16; ++i) { acc0[i] = 0.f; acc1[i] = 0.f; }

    // prologue: stage chunks 0,1,2 (12 loads/wave outstanding)
    #pragma unroll
    for (int p = 0; p < 3; ++p)
        #pragma unroll
        for (int s = 0; s < 4; ++s)
            gll16(sbase[s] + p * 256, lds + p * 32768 + ((wv * 4 + s) * 64) * 16);

    // read-side byte offsets (swizzled). A row-chunk = [hi|lo k0-31][hi|lo k32-63]
    const int sa  = (kq >> 1) * 8 + (kq & 1) * 2 + hi5;   // A hi slot
    const int ra0 = lo5, ra1 = 32 + lo5;
    const int offAh0 = ra0 * 256 + (((sa)     ^ (ra0 & 15)) << 4);
    const int offAl0 = ra0 * 256 + (((sa + 4) ^ (ra0 & 15)) << 4);
    const int offAh1 = ra1 * 256 + (((sa)     ^ (ra1 & 15)) << 4);
    const int offAl1 = ra1 * 256 + (((sa + 4) ^ (ra1 & 15)) << 4);
    const int rb  = mt * 32 + lo5;
    const int sb  = kq * 4 + hi5 * 2;                     // B slot (fp32)
    const int offB0 = 16384 + rb * 256 + (((sb)     ^ (rb & 15)) << 4);
    const int offB1 = 16384 + rb * 256 + (((sb + 1) ^ (rb & 15)) << 4);

    for (int c = 0; c < NCH; ++c) {
        if (c < NCH - 2) {
            asm volatile("s_waitcnt vmcnt(8)" ::: "memory");   // chunk c landed
        } else if (c == NCH - 2) {
            asm volatile("s_waitcnt vmcnt(4)" ::: "memory");
        } else {
            asm volatile("s_waitcnt vmcnt(0)" ::: "memory");
        }
        __builtin_amdgcn_s_barrier();

        const char* bufb = lds + (c & 3) * 32768;
        const bf16x8 ah0 = *reinterpret_cast<const bf16x8*>(bufb + offAh0);
        const bf16x8 al0 = *reinterpret_cast<const bf16x8*>(bufb + offAl0);
        const bf16x8 ah1 = *reinterpret_cast<const bf16x8*>(bufb + offAh1);
        const bf16x8 al1 = *reinterpret_cast<const bf16x8*>(bufb + offAl1);
        const float4 b1  = *reinterpret_cast<const float4*>(bufb + offB0);
        const float4 b2  = *reinterpret_cast<const float4*>(bufb + offB1);

        bf16x8 bh, bl;
        cvt8(b1, b2, bh, bl);

        if (c + 3 < NCH) {             // issue chunk c+3 (stays in flight)
            #pragma unroll
            for (int s = 0; s < 4; ++s)
                gll16(sbase[s] + (c + 3) * 256,
                      lds + ((c + 3) & 3) * 32768 + ((wv * 4 + s) * 64) * 16);
        }

        acc0 = MFMA(ah0, bh, acc0);    // hi*hi
        acc1 = MFMA(ah1, bh, acc1);
        acc0 = MFMA(ah0, bl, acc0);    // hi*lo
        acc1 = MFMA(ah1, bl, acc1);
        acc0 = MFMA(al0, bh, acc0);    // lo*hi
        acc1 = MFMA(al1, bh, acc1);
    }

    // ---- K-slice reduction: kq 1..3 write partials, kq 0 accumulates -------
    __syncthreads();
    float* S = reinterpret_cast<float*>(lds);    // 192*65*4B = 49920 < 131072
    if (kq != 0) {
        const int base = ((mt * 3 + (kq - 1)) * 32 + lo5) * 65;
        #pragma unroll
        for (int r = 0; r < 16; ++r) {
            const int e0 = (r & 3) + 8 * (r >> 2) + 4 * hi5;
            S[base + e0]      = acc0[r];
            S[base + 32 + e0] = acc1[r];
        }
    }
    __syncthreads();
    if (kq != 0) return;
    #pragma unroll
    for (int q = 0; q < 3; ++q) {
        const int base = ((mt * 3 + q) * 32 + lo5) * 65;
        #pragma unroll
        for (int r = 0; r < 16; ++r) {
            const int e0 = (r & 3) + 8 * (r >> 2) + 4 * hi5;
            acc0[r] += S[base + e0];
            acc1[r] += S[base + 32 + e0];
        }
    }

    // ---- per-lane top-3 over 32 held experts (e ascending => stable) -------
    float m1 = NEGF, m2 = NEGF, m3 = NEGF;
    int   i1 = 0, i2 = 0;
    #pragma unroll
    for (int r = 0; r < 16; ++r) {
        const float v = acc0[r];
        const int   e = (r & 3) + 8 * (r >> 2) + 4 * hi5;
        if (v > m1)      { m3 = m2; m2 = m1; i2 = i1; m1 = v; i1 = e; }
        else if (v > m2) { m3 = m2; m2 = v; i2 = e; }
        else if (v > m3) { m3 = v; }
    }
    #pragma unroll
    for (int r = 0; r < 16; ++r) {
        const float v = acc1[r];
        const int   e = 32 + (r & 3) + 8 * (r >> 2) + 4 * hi5;
        if (v > m1)      { m3 = m2; m2 = m1; i2 = i1; m1 = v; i1 = e; }
        else if (v > m2) { m3 = m2; m2 = v; i2 = e; }
        else if (v > m3) { m3 = v; }
    }

    // ---- merge sorted triples across lane pair (l, l^32): same token -------
    const float n1 = __shfl_xor(m1, 32), n2 = __shfl_xor(m2, 32), n3 = __shfl_xor(m3, 32);
    const int   j1 = __shfl_xor(i1, 32), j2 = __shfl_xor(i2, 32);

    float a1, a2, a3, b1, b2, b3; int ia1, ia2, ib1, ib2;
    const bool aF = (m1 > n1) || (m1 == n1 && i1 < j1);
    if (aF) { a1=m1; a2=m2; a3=m3; ia1=i1; ia2=i2; b1=n1; b2=n2; b3=n3; ib1=j1; ib2=j2; }
    else    { a1=n1; a2=n2; a3=n3; ia1=j1; ia2=j2; b1=m1; b2=m2; b3=m3; ib1=i1; ib2=i2; }

    const float o1 = a1; const int oi1 = ia1;
    float o2, o3; int oi2;
    const bool a2F = (a2 > b1) || (a2 == b1 && ia2 < ib1);
    if (a2F) { o2 = a2; oi2 = ia2; o3 = (a3 > b1) ? a3 : b1; }
    else     { o2 = b1; oi2 = ib1; o3 = (a2 > b2) ? a2 : b2; }

    if (hi5 == 0) {
        const int t = t0 + mt * 32 + lo5;
        const float r = expf(o2 - o1);
        const float s = 1.0f + r;
        out[2 * t + 0]        = (float)oi1;
        out[2 * t + 1]        = (float)oi2;
        out[woff + 2 * t + 0] = 1.0f / s;
        out[woff + 2 * t + 1] = r / s;
        if ((o1 - o2 < TAU) || (o2 - o3 < TAU)) {
            const int pos = atomicAdd(wl, 1);
            if (pos < wlcap) wl[1 + pos] = t;
        }
    }
}

// ---- Pass 2: fp64 refine, coalesced-W, block per token, 4-wave K-split ----
__global__ __launch_bounds__(256) void moe_refine_fp64(
    const float* __restrict__ x, const float* __restrict__ w,
    float* __restrict__ out, int woff,
    const int* __restrict__ wl, int wlcap)
{
    __shared__ double Sd[3][NE];
    const int lane = threadIdx.x & 63;
    const int wv   = threadIdx.x >> 6;
    const int ks   = wv * 512;
    int cnt = wl[0];
    if (cnt > wlcap) cnt = wlcap;

    for (int i = blockIdx.x; i < cnt; i += gridDim.x) {
        const int t = wl[1 + i];

        const float4 xa = LD4(&x[(size_t)t * H + ks + lane * 4]);
        const float4 xb = LD4(&x[(size_t)t * H + ks + 256 + lane * 4]);
        const double x0 = xa.x, x1 = xa.y, x2 = xa.z, x3 = xa.w;
        const double x4 = xb.x, x5 = xb.y, x6 = xb.z, x7 = xb.w;

        double myacc = 0.0;
        #pragma unroll 4
        for (int e = 0; e < NE; ++e) {
            const float4 wa = LD4(&w[(size_t)e * H + ks + lane * 4]);
            const float4 wb = LD4(&w[(size_t)e * H + ks + 256 + lane * 4]);
            double sA = 0.0, sB = 0.0;
            sA = fma((double)wa.x, x0, sA); sA = fma((double)wa.y, x1, sA);
            sA = fma((double)wa.z, x2, sA); sA = fma((double)wa.w, x3, sA);
            sB = fma((double)wb.x, x4, sB); sB = fma((double)wb.y, x5, sB);
            sB = fma((double)wb.z, x6, sB); sB = fma((double)wb.w, x7, sB);
            double s = sA + sB;
            #pragma unroll
            for (int off = 1; off < 64; off <<= 1)
                s += __shfl_xor(s, off);
            if (lane == e) myacc = s;
        }

        if (wv > 0) Sd[wv - 1][lane] = myacc;
        __syncthreads();
        if (wv == 0) {
            const double acc = ((myacc + Sd[0][lane]) + Sd[1][lane]) + Sd[2][lane];

            double v = acc; int bi = lane;
            #pragma unroll
            for (int off = 32; off > 0; off >>= 1) {
                double ov = __shfl_xor(v, off);
                int    oi = __shfl_xor(bi, off);
                if (ov > v || (ov == v && oi < bi)) { v = ov; bi = oi; }
            }
            const double m1 = v; const int i1 = bi;

            double v2 = (lane == i1) ? -1.0e300 : acc; int b2 = lane;
            #pragma unroll
            for (int off = 32; off > 0; off >>= 1) {
                double ov = __shfl_xor(v2, off);
                int    oi = __shfl_xor(b2, off);
                if (ov > v2 || (ov == v2 && oi < b2)) { v2 = ov; b2 = oi; }
            }
            const double m2 = v2; const int i2 = b2;

            if (lane == 0) {
                const double r = exp(m2 - m1);
                const double s = 1.0 + r;
                out[2 * t + 0]        = (float)i1;
                out[2 * t + 1]        = (float)i2;
                out[woff + 2 * t + 0] = (float)(1.0 / s);
                out[woff + 2 * t + 1] = (float)(r / s);
            }
        }
        __syncthreads();
    }
}

extern "C" void kernel_launch(void* const* d_in, const int* in_sizes, int n_in,
                              void* d_out, int out_size, void* d_ws, size_t ws_size,
                              hipStream_t stream) {
    const float* x   = (const float*)d_in[0];
    const float* wgt = (const float*)d_in[1];
    float* out = (float*)d_out;

    const int T    = in_sizes[0] / H;   // 16384
    const int woff = out_size / 2;      // 32768

    int*    wl = (int*)d_ws;
    __bf16* wp = (__bf16*)((char*)d_ws + 131072);   // 512 KB prepacked W
    int wlcap = T;

    // allow 128 KB dynamic LDS (idempotent; ignore result)
    (void)hipFuncSetAttribute((const void*)moe_gate_mfma,
                              hipFuncAttributeMaxDynamicSharedMemorySize, 131072);

    prep_w<<<dim3(NE), dim3(256), 0, stream>>>(wgt, wp, wl);

    moe_gate_mfma<<<dim3(T / TOKB), dim3(512), 131072, stream>>>(
        x, wp, out, woff, wl, wlcap);

    moe_refine_fp64<<<dim3(512), dim3(256), 0, stream>>>(
        x, wgt, out, woff, wl, wlcap);
}